// Round 4
// baseline (1123.917 us; speedup 1.0000x reference)
//
#include <hip/hip_runtime.h>
#include <hip/hip_bf16.h>
#include <math.h>

typedef __bf16 bf16x8 __attribute__((ext_vector_type(8)));
typedef float  f32x4  __attribute__((ext_vector_type(4)));
typedef float  f32x16 __attribute__((ext_vector_type(16)));

#define MFMA16(a, b, c) __builtin_amdgcn_mfma_f32_16x16x32_bf16((a), (b), (c), 0, 0, 0)
#define MFMA32(a, b, c) __builtin_amdgcn_mfma_f32_32x32x16_bf16((a), (b), (c), 0, 0, 0)

static constexpr int    kB  = 16;
static constexpr int    kS  = 2048;
static constexpr int    kC  = 512;
static constexpr size_t kNE = (size_t)kB * kS * kC;  // 16777216

static __device__ __forceinline__ void split_bf16(float v, __bf16 &hi, __bf16 &lo) {
  hi = (__bf16)v;                 // RNE
  lo = (__bf16)(v - (float)hi);   // residual, ~2^-17 combined rel error
}

// global -> LDS direct DMA, 16B per lane. LDS dest is wave-uniform base + lane*16.
static __device__ __forceinline__ void gload16(const void* g, void* l) {
  __builtin_amdgcn_global_load_lds(
      (const __attribute__((address_space(1))) char*)g,
      (__attribute__((address_space(3))) char*)l, 16, 0, 0);
}

// Byte offset into a [rows][64] bf16 tile (128 B rows), XOR-swizzled in 16 B chunks.
static __device__ __forceinline__ int swzb(int row, int e) {
  return ((row << 7) + (e << 1)) ^ ((row & 7) << 4);
}

// Split 16 staged fp32 into bf16 hi/lo and store to swizzled LDS tiles.
static __device__ __forceinline__ void split_store16_swz(
    float4 v0, float4 v1, float4 v2, float4 v3, char* hi, char* lo, int row, int e0) {
  float vv[16] = {v0.x, v0.y, v0.z, v0.w, v1.x, v1.y, v1.z, v1.w,
                  v2.x, v2.y, v2.z, v2.w, v3.x, v3.y, v3.z, v3.w};
  bf16x8 h0, h1, l0, l1;
#pragma unroll
  for (int i = 0; i < 8; ++i) {
    __bf16 a, b;
    split_bf16(vv[i], a, b);     h0[i] = a; l0[i] = b;
    split_bf16(vv[8 + i], a, b); h1[i] = a; l1[i] = b;
  }
  *(bf16x8*)(hi + swzb(row, e0))     = h0;
  *(bf16x8*)(hi + swzb(row, e0 + 8)) = h1;
  *(bf16x8*)(lo + swzb(row, e0))     = l0;
  *(bf16x8*)(lo + swzb(row, e0 + 8)) = l1;
}

// ---------------- K1a: t = tanh(x'), split to bf16 hi/lo ----------------
__global__ __launch_bounds__(256) void k_tanh_split(
    const float* __restrict__ xp, __bf16* __restrict__ th, __bf16* __restrict__ tl) {
  size_t i = ((size_t)blockIdx.x * 256 + threadIdx.x) * 8;
  float4 a = *(const float4*)(xp + i);
  float4 b = *(const float4*)(xp + i + 4);
  float v[8] = {a.x, a.y, a.z, a.w, b.x, b.y, b.z, b.w};
  bf16x8 h, l;
#pragma unroll
  for (int k = 0; k < 8; ++k) {
    float t = tanhf(v[k]);
    __bf16 hh, ll;
    split_bf16(t, hh, ll);
    h[k] = hh; l[k] = ll;
  }
  *(bf16x8*)(th + i) = h;
  *(bf16x8*)(tl + i) = l;
}

// ---------------- K1c: x (fp32 [b][t][c]) -> bf16 transposed [b][c][t] ----------------
__global__ __launch_bounds__(256) void k_transpose_x(
    const float* __restrict__ x, __bf16* __restrict__ xbt) {
  __shared__ float tile[64][65];
  int bid = blockIdx.x;              // 16 * 32 * 8 = 4096
  int b   = bid >> 8;
  int t0  = ((bid >> 3) & 31) * 64;
  int c0  = (bid & 7) * 64;
  int row = threadIdx.x >> 2;        // 0..63
  int seg = threadIdx.x & 3;         // 0..3 (16 elems each)
  const float* src = x + (size_t)(b * kS + t0 + row) * kC + c0 + seg * 16;
  float4 v0 = *(const float4*)(src + 0);
  float4 v1 = *(const float4*)(src + 4);
  float4 v2 = *(const float4*)(src + 8);
  float4 v3 = *(const float4*)(src + 12);
  float vv[16] = {v0.x, v0.y, v0.z, v0.w, v1.x, v1.y, v1.z, v1.w,
                  v2.x, v2.y, v2.z, v2.w, v3.x, v3.y, v3.z, v3.w};
#pragma unroll
  for (int i = 0; i < 16; ++i) tile[row][seg * 16 + i] = vv[i];
  __syncthreads();
  bf16x8 o0, o1;
#pragma unroll
  for (int i = 0; i < 8; ++i) o0[i] = (__bf16)tile[seg * 16 + i][row];
#pragma unroll
  for (int i = 0; i < 8; ++i) o1[i] = (__bf16)tile[seg * 16 + 8 + i][row];
  __bf16* dst = xbt + (size_t)(b * kC + c0 + row) * kS + t0 + seg * 16;
  *(bf16x8*)(dst)     = o0;
  *(bf16x8*)(dst + 8) = o1;
}

// ---------------- K1b: q = x' @ W^T + bias, fp32-accurate via split-bf16 3-MFMA ----------------
__global__ __launch_bounds__(256) void k_qgemm(
    const float* __restrict__ xp, const float* __restrict__ W,
    const float* __restrict__ bias, __bf16* __restrict__ qh, __bf16* __restrict__ ql) {
  __shared__ __align__(16) char lds[32768];
  char* Ah = lds;             // [64][64] swizzled
  char* Al = lds + 8192;
  char* Bh = lds + 16384;     // [64][64] swizzled (W rows d, cols c)
  char* Bl = lds + 24576;

  int bid = blockIdx.x;         // 512 m-tiles * 8 n-tiles
  int n0  = (bid & 7) * 64;
  int m0  = (bid >> 3) * 64;

  int tid  = threadIdx.x;
  int lane = tid & 63;
  int wave = tid >> 6;
  int qd   = lane >> 4;
  int cl   = lane & 15;
  int row  = tid >> 2;
  int seg  = tid & 3;

  f32x4 acc[4] = {};
  const float* srcA = xp + (size_t)(m0 + row) * kC + seg * 16;
  const float* srcB = W  + (size_t)(n0 + row) * kC + seg * 16;

  float4 va0, va1, va2, va3, vb0, vb1, vb2, vb3;
  auto load_ab = [&](int kc) {
    const float* a = srcA + kc * 64;
    va0 = *(const float4*)(a);      va1 = *(const float4*)(a + 4);
    va2 = *(const float4*)(a + 8);  va3 = *(const float4*)(a + 12);
    const float* bb = srcB + kc * 64;
    vb0 = *(const float4*)(bb);     vb1 = *(const float4*)(bb + 4);
    vb2 = *(const float4*)(bb + 8); vb3 = *(const float4*)(bb + 12);
  };

  load_ab(0);
  for (int kc = 0; kc < 8; ++kc) {
    split_store16_swz(va0, va1, va2, va3, Ah, Al, row, seg * 16);
    split_store16_swz(vb0, vb1, vb2, vb3, Bh, Bl, row, seg * 16);
    __syncthreads();
    if (kc < 7) load_ab(kc + 1);   // fly next tile's loads under the MFMAs
    __builtin_amdgcn_s_setprio(1);
#pragma unroll
    for (int ks = 0; ks < 2; ++ks) {
      int ka = ks * 32 + qd * 8;
      bf16x8 ah = *(const bf16x8*)(Ah + swzb(wave * 16 + cl, ka));
      bf16x8 al = *(const bf16x8*)(Al + swzb(wave * 16 + cl, ka));
#pragma unroll
      for (int j = 0; j < 4; ++j) {
        bf16x8 bh = *(const bf16x8*)(Bh + swzb(j * 16 + cl, ka));
        bf16x8 bl = *(const bf16x8*)(Bl + swzb(j * 16 + cl, ka));
        acc[j] = MFMA16(ah, bh, acc[j]);
        acc[j] = MFMA16(ah, bl, acc[j]);
        acc[j] = MFMA16(al, bh, acc[j]);
      }
    }
    __builtin_amdgcn_s_setprio(0);
    __syncthreads();
  }
#pragma unroll
  for (int j = 0; j < 4; ++j) {
    int d = n0 + j * 16 + cl;
    float bv = bias[d];
#pragma unroll
    for (int r = 0; r < 4; ++r) {
      int m = m0 + wave * 16 + qd * 4 + r;
      float v = acc[j][r] + bv;
      __bf16 h, l;
      split_bf16(v, h, l);
      qh[(size_t)m * kC + d] = h;
      ql[(size_t)m * kC + d] = l;
    }
  }
}

// ---------------- K2: fused flash attention, 128-row blocks, 512 threads ----------------
// All staging via global_load_lds DMA (zero staging VGPRs), double-buffered.
// XOR-swizzled tiles via pre-swizzled GLOBAL source + linear LDS dest.
// 32x32x16 MFMA everywhere. Wave grid: 4 row-groups (wg) x 2 col-groups (cg).
//
// LDS map (163840 B = 160 KiB):
//   statm @0, stats @1024 (alias Ah0 rows 0-15; live only post-score..B2,
//                          buf0 is re-staged at PV step 3, after last stat read)
//   buf0 @0      : Ah 16K | Al 16K | Bh 16K | Bl 16K   (score kc even)
//   buf1 @65536  : same                                 (score kc odd)
//   P     @65536 : [128 s][128 t] bf16, 32K (alias Ah1/Al1; written post-score,
//                  read into pa regs after B2; NEVER overwritten within a tt)
//   XEVEN @98304 : two [64 ch][128 t] tiles (alias Bh1/Bl1; steps 0,2)
//   XODD  @131072: two [64 ch][128 t] tiles (DEDICATED; steps 1,3)  <- r3 bugfix
__global__ __launch_bounds__(512, 2) void k_attn(
    const __bf16* __restrict__ th, const __bf16* __restrict__ tl,
    const __bf16* __restrict__ qh, const __bf16* __restrict__ ql,
    const __bf16* __restrict__ xbt, float* __restrict__ out) {
  __shared__ __align__(16) char lds[163840];
  char*  P     = lds + 65536;
  float* statm = (float*)(lds);
  float* stats = (float*)(lds + 1024);
  const int XEVEN = 98304, XODD = 131072;

  int bid = blockIdx.x;          // 256 = 16 batches * 16 s-tiles
  int b   = bid >> 4;
  int s0  = (bid & 15) * 128;

  int tid  = threadIdx.x;
  int lane = tid & 63;
  int wv   = tid >> 6;           // 0..7
  int l31  = lane & 31;
  int lh   = lane >> 5;
  int wg   = wv >> 1;            // row group: rows wg*32..+32
  int cg   = wv & 1;             // col group: score cols cg*64, PV cols cg*256

  const float LOG2E = 1.4426950408889634f;

  float m_r[16], l_r[16];
#pragma unroll
  for (int i = 0; i < 16; ++i) { m_r[i] = -INFINITY; l_r[i] = 0.f; }
  f32x16 O[8] = {};              // O[j]: rows wg*32+rowl(i), col cg*256+(j>>1)*64+(j&1)*32+l31

  // ---- DMA staging (pre-swizzled global source, linear LDS dest) ----
  // score tiles: [128 rows][8 chunks of 16B]; slot s: r=s>>3, pos p=s&7 holds chunk c=p^(r&7).
  auto stage_score = [&](int kc, int bufsel, int t0q) {
    char* Ahd = lds + bufsel * 65536;
    char* Ald = Ahd + 16384;
    char* Bhd = Ahd + 32768;
    char* Bld = Ahd + 49152;
#pragma unroll
    for (int u = 0; u < 2; ++u) {
      int slot = wv * 128 + u * 64 + lane;
      int r = slot >> 3;
      int c = (slot & 7) ^ (r & 7);
      size_t gA = (size_t)(b * kS + s0 + r) * kC + kc * 64 + c * 8;
      size_t gB = (size_t)(b * kS + t0q + r) * kC + kc * 64 + c * 8;
      int ldoff = (wv * 128 + u * 64) * 16;   // wave-uniform
      gload16(th + gA, Ahd + ldoff);
      gload16(tl + gA, Ald + ldoff);
      gload16(qh + gB, Bhd + ldoff);
      gload16(ql + gB, Bld + ldoff);
    }
  };
  // Xt tile: [64 ch][16 chunks of 16B]; slot s: r=s>>4, p=s&15 holds chunk c=p^(r&7).
  auto stage_xpair = [&](int step, int pairbase, int t0q) {
#pragma unroll
    for (int half = 0; half < 2; ++half) {
      char* dst = lds + pairbase + half * 16384;
#pragma unroll
      for (int u = 0; u < 2; ++u) {
        int slot = wv * 128 + u * 64 + lane;
        int r = slot >> 4;
        int c = (slot & 15) ^ (r & 7);
        size_t g = ((size_t)b * kC + half * 256 + step * 64 + r) * kS + t0q + c * 8;
        gload16(xbt + g, dst + (wv * 128 + u * 64) * 16);
      }
    }
  };

  stage_score(0, 0, 0);          // prologue: tt=0, kc=0 -> buf0
  __syncthreads();

  const int arow = wg * 32 + l31;          // score A row (s)
  const int prow = wg * 32 + l31;          // PV A row (s)

  for (int tt = 0; tt < 16; ++tt) {
    int t0 = tt * 128;
    f32x16 S0 = {}, S1 = {};
    // ----- score: S[128 x 128] = T . Q^T over K=512, 32x32x16, double-buffered DMA -----
    for (int kc = 0; kc < 8; ++kc) {
      if (kc < 7) stage_score(kc + 1, (kc + 1) & 1, t0);
      const char* cb  = lds + (kc & 1) * 65536;
      const char* cAh = cb, *cAl = cb + 16384, *cBh = cb + 32768, *cBl = cb + 49152;
      __builtin_amdgcn_s_setprio(1);
#pragma unroll
      for (int ks = 0; ks < 4; ++ks) {
        int ach = ((ks * 2 + lh) ^ (arow & 7)) * 16;
        bf16x8 ah = *(const bf16x8*)(cAh + arow * 128 + ach);
        bf16x8 al = *(const bf16x8*)(cAl + arow * 128 + ach);
#pragma unroll
        for (int tile = 0; tile < 2; ++tile) {
          int trow = cg * 64 + tile * 32 + l31;
          int bch  = ((ks * 2 + lh) ^ (trow & 7)) * 16;
          bf16x8 bh = *(const bf16x8*)(cBh + trow * 128 + bch);
          bf16x8 bl = *(const bf16x8*)(cBl + trow * 128 + bch);
          if (tile == 0) {
            S0 = MFMA32(ah, bh, S0); S0 = MFMA32(ah, bl, S0); S0 = MFMA32(al, bh, S0);
          } else {
            S1 = MFMA32(ah, bh, S1); S1 = MFMA32(ah, bl, S1); S1 = MFMA32(al, bh, S1);
          }
        }
      }
      __builtin_amdgcn_s_setprio(0);
      __syncthreads();
    }
    // ----- online softmax; rows r(i) = (i&3)+8*(i>>2)+4*lh, per-lane 2 cols/row -----
    float rm[16];
#pragma unroll
    for (int i = 0; i < 16; ++i) rm[i] = fmaxf(S0[i], S1[i]);
#pragma unroll
    for (int mk = 1; mk < 32; mk <<= 1)
#pragma unroll
      for (int i = 0; i < 16; ++i) rm[i] = fmaxf(rm[i], __shfl_xor(rm[i], mk, 64));
    if (l31 == 0) {
#pragma unroll
      for (int i = 0; i < 16; ++i) {
        int rl = (i & 3) + 8 * (i >> 2) + 4 * lh;
        statm[cg * 128 + wg * 32 + rl] = rm[i];
      }
    }
    __syncthreads();                        // B1
    // issue PV step0 Xt pair; flies under exp/sum VALU work (drains at B2)
    stage_xpair(0, XEVEN, t0);
    float alpha[16];
#pragma unroll
    for (int i = 0; i < 16; ++i) {
      int rl = (i & 3) + 8 * (i >> 2) + 4 * lh;
      float om = statm[(cg ^ 1) * 128 + wg * 32 + rl];
      float M  = fmaxf(m_r[i], fmaxf(rm[i], om));
      alpha[i] = exp2f((m_r[i] - M) * LOG2E);
      m_r[i] = M;
      l_r[i] *= alpha[i];
    }
#pragma unroll
    for (int j = 0; j < 8; ++j)
#pragma unroll
      for (int i = 0; i < 16; ++i) O[j][i] *= alpha[i];
    float rs[16];
#pragma unroll
    for (int i = 0; i < 16; ++i) {
      S0[i] = exp2f((S0[i] - m_r[i]) * LOG2E);
      S1[i] = exp2f((S1[i] - m_r[i]) * LOG2E);
      rs[i] = S0[i] + S1[i];
    }
#pragma unroll
    for (int mk = 1; mk < 32; mk <<= 1)
#pragma unroll
      for (int i = 0; i < 16; ++i) rs[i] += __shfl_xor(rs[i], mk, 64);
    if (l31 == 0) {
#pragma unroll
      for (int i = 0; i < 16; ++i) {
        int rl = (i & 3) + 8 * (i >> 2) + 4 * lh;
        stats[cg * 128 + wg * 32 + rl] = rs[i];
      }
    }
    // write P (C-layout -> A-layout via LDS); region dead (was Ah1/Al1)
#pragma unroll
    for (int tile = 0; tile < 2; ++tile)
#pragma unroll
      for (int i = 0; i < 16; ++i) {
        int s = wg * 32 + (i & 3) + 8 * (i >> 2) + 4 * lh;
        int t = cg * 64 + tile * 32 + l31;
        int off = s * 256 + ((((t >> 3) ^ (s & 7)) << 4) | ((t & 7) << 1));
        *(__bf16*)(P + off) = (__bf16)(tile ? S1[i] : S0[i]);
      }
    __syncthreads();                        // B2: stats + P complete, Xt step0 drained
#pragma unroll
    for (int i = 0; i < 16; ++i) {
      int rl = (i & 3) + 8 * (i >> 2) + 4 * lh;
      l_r[i] += rs[i] + stats[(cg ^ 1) * 128 + wg * 32 + rl];
    }
    bf16x8 pa[8];
#pragma unroll
    for (int ks = 0; ks < 8; ++ks) {
      int ch = ((ks * 2 + lh) ^ (prow & 7)) * 16;
      pa[ks] = *(const bf16x8*)(P + prow * 256 + ch);
    }
    __syncthreads();                        // B3 (defensive): all pa reads done
    // ----- PV: O[128 x 512] += P[128 x 128] . Xbt[128 x 512], 32x32x16 -----
#pragma unroll
    for (int step = 0; step < 4; ++step) {
      if (step < 3)      stage_xpair(step + 1, ((step + 1) & 1) ? XODD : XEVEN, t0);
      else if (tt < 15)  stage_score(0, 0, t0 + 128);     // next tt's kc=0 -> buf0
      const char* xbb = lds + ((step & 1) ? XODD : XEVEN) + cg * 16384;
      __builtin_amdgcn_s_setprio(1);
#pragma unroll
      for (int ks = 0; ks < 8; ++ks)
#pragma unroll
        for (int tile = 0; tile < 2; ++tile) {
          int xrow = tile * 32 + l31;
          int ch = ((ks * 2 + lh) ^ (xrow & 7)) * 16;
          bf16x8 xb = *(const bf16x8*)(xbb + xrow * 256 + ch);
          O[step * 2 + tile] = MFMA32(pa[ks], xb, O[step * 2 + tile]);
        }
      __builtin_amdgcn_s_setprio(0);
      __syncthreads();
    }
  }
  // ----- epilogue: out = tanh(O / l) -----
#pragma unroll
  for (int i = 0; i < 16; ++i) {
    int rl = (i & 3) + 8 * (i >> 2) + 4 * lh;
    float inv = __builtin_amdgcn_rcpf(l_r[i]);   // l >= 1 always
    size_t rowoff = ((size_t)b * kS + s0 + wg * 32 + rl) * kC;
#pragma unroll
    for (int j = 0; j < 8; ++j) {
      float v = O[j][i] * inv;
      float e = exp2f(2.f * LOG2E * v);          // e^{2v}; |v| <= ~6, no overflow
      out[rowoff + cg * 256 + (j >> 1) * 64 + (j & 1) * 32 + l31] =
          1.f - 2.f * __builtin_amdgcn_rcpf(e + 1.f);
    }
  }
}

extern "C" void kernel_launch(void* const* d_in, const int* in_sizes, int n_in,
                              void* d_out, int out_size, void* d_ws, size_t ws_size,
                              hipStream_t stream) {
  const float* x    = (const float*)d_in[0];
  const float* xp   = (const float*)d_in[1];
  const float* W    = (const float*)d_in[2];
  const float* bias = (const float*)d_in[3];
  float* out = (float*)d_out;

  // workspace layout (bf16): t_hi | t_lo | q_hi | q_lo | x_bt  -> 5 * 16.78M * 2B = 160 MiB
  __bf16* ws  = (__bf16*)d_ws;
  __bf16* th  = ws;
  __bf16* tl  = ws + kNE;
  __bf16* qh  = ws + 2 * kNE;
  __bf16* ql  = ws + 3 * kNE;
  __bf16* xbt = ws + 4 * kNE;

  k_tanh_split<<<8192, 256, 0, stream>>>(xp, th, tl);
  k_transpose_x<<<4096, 256, 0, stream>>>(x, xbt);
  k_qgemm<<<4096, 256, 0, stream>>>(xp, W, bias, qh, ql);
  k_attn<<<256, 512, 0, stream>>>(th, tl, qh, ql, xbt, out);
}